// Round 3
// baseline (53.198 us; speedup 1.0000x reference)
//
#include <hip/hip_runtime.h>

// B=4096, K=64, N=256 (fixed by the problem).
// d_out = [pred (B*K floats)] ++ [y (K*N*K floats)], float32.
// Single fused persistent-grid kernel:
//   - wave (64 lanes) per segment: lane l loads float4 x4[seg*64+l]
//     (64*16B = 1024B = the whole 256-float segment, fully coalesced),
//     6-step shfl reduce, lane 0 stores pred[seg]. Grid-stride over segments.
//   - y tail: y[r][c] = (r/N == c), computed analytically, <=1 float4/thread.
// Native vector type: __builtin_nontemporal_* rejects HIP_vector_type.

typedef float f32x4 __attribute__((ext_vector_type(4)));

constexpr int K = 64;
constexpr int N = 256;
constexpr int BLOCKS = 2048;   // 8 blocks/CU on 256 CUs (G11: cap + grid-stride)
constexpr int TPB = 256;

__global__ __launch_bounds__(TPB) void fused_kernel(const f32x4* __restrict__ x4,
                                                    float* __restrict__ pred,
                                                    f32x4* __restrict__ y4,
                                                    int total_seg) {
    const int lane = threadIdx.x & 63;
    const int wave = threadIdx.x >> 6;
    const int wave_stride = gridDim.x * (TPB / 64);

    for (long long seg = (long long)blockIdx.x * (TPB / 64) + wave;
         seg < total_seg; seg += wave_stride) {
        f32x4 v = __builtin_nontemporal_load(&x4[seg * (N / 4) + lane]);
        float s = (v.x + v.y) + (v.z + v.w);
        #pragma unroll
        for (int off = 32; off >= 1; off >>= 1)
            s += __shfl_down(s, off, 64);
        if (lane == 0) __builtin_nontemporal_store(s, &pred[seg]);
    }

    // y: K*N*K/4 = 262144 float4s; grid has 524288 threads -> <=1 per thread.
    const int tid = blockIdx.x * TPB + threadIdx.x;
    const int nthreads = gridDim.x * TPB;
    for (int i = tid; i < (K * N * K) / 4; i += nthreads) {
        const int r = i >> 4;          // / (K/4): row in [0, K*N)
        const int cb = (i & 15) << 2;  // column base
        const int hot = r >> 8;        // r / N
        f32x4 v;
        v.x = (cb + 0 == hot) ? 1.0f : 0.0f;
        v.y = (cb + 1 == hot) ? 1.0f : 0.0f;
        v.z = (cb + 2 == hot) ? 1.0f : 0.0f;
        v.w = (cb + 3 == hot) ? 1.0f : 0.0f;
        __builtin_nontemporal_store(v, &y4[i]);
    }
}

extern "C" void kernel_launch(void* const* d_in, const int* in_sizes, int n_in,
                              void* d_out, int out_size, void* d_ws, size_t ws_size,
                              hipStream_t stream) {
    const float* x = (const float*)d_in[0];
    float* out = (float*)d_out;

    const int B = in_sizes[0] / (K * N);       // 4096
    const int total_seg = B * K;               // 262144
    float* pred = out;                         // B*K floats
    float* y = out + (size_t)B * K;            // K*N*K floats

    fused_kernel<<<BLOCKS, TPB, 0, stream>>>(
        reinterpret_cast<const f32x4*>(x), pred,
        reinterpret_cast<f32x4*>(y), total_seg);
}

// Round 4
// 44.155 us; speedup vs baseline: 1.2048x; 1.2048x over previous
//
#include <hip/hip_runtime.h>

// B=4096, K=64, N=256 (fixed by the problem).
// d_out = [pred (B*K floats)] ++ [y (K*N*K floats)], float32.
//
// Segment-sum layout: 16 lanes per segment, 4 segments per wave.
//   lane = q*16+i (q=seg-in-chunk, i=lane-in-seg). Lane loads 4 independent
//   float4s at (seg*64 + j*16 + i), j=0..3 -> per instruction the wave covers
//   4 contiguous 256B runs (coalesced), with 4 loads in flight (ILP), then a
//   16-float in-register sum + 4-step __shfl_xor (intra-16 lane group).
// This replaces R3's wave-per-segment form (1 outstanding load + 6-deep
// ds_bpermute chain per KiB) which underperformed (53.2us vs 51.4).

typedef float f32x4 __attribute__((ext_vector_type(4)));

constexpr int K = 64;
constexpr int N = 256;
constexpr int BLOCKS = 2048;   // 8 blocks/CU on 256 CUs, grid-stride (G11)
constexpr int TPB = 256;

__global__ __launch_bounds__(TPB) void fused_kernel(const f32x4* __restrict__ x4,
                                                    float* __restrict__ pred,
                                                    f32x4* __restrict__ y4,
                                                    int total_chunks) {
    const int lane = threadIdx.x & 63;
    const int wave = threadIdx.x >> 6;
    const int q = lane >> 4;       // segment within 4-seg chunk
    const int i = lane & 15;       // lane within segment
    const int gwave = blockIdx.x * (TPB / 64) + wave;
    const int nwaves = gridDim.x * (TPB / 64);

    for (int c = gwave; c < total_chunks; c += nwaves) {
        // chunk c = 4 segments = 256 float4s (4 KiB)
        const long long base = (long long)c * 256 + q * 64 + i;
        f32x4 v0 = x4[base +  0];
        f32x4 v1 = x4[base + 16];
        f32x4 v2 = x4[base + 32];
        f32x4 v3 = x4[base + 48];
        f32x4 t = (v0 + v1) + (v2 + v3);
        float s = (t.x + t.y) + (t.z + t.w);
        // reduce across the 16 lanes of this segment (xor of bits 0..3 only)
        s += __shfl_xor(s, 1, 64);
        s += __shfl_xor(s, 2, 64);
        s += __shfl_xor(s, 4, 64);
        s += __shfl_xor(s, 8, 64);
        if (i == 0) pred[c * 4 + q] = s;
    }

    // y: K*N*K/4 = 262144 float4s; grid has 524288 threads -> <=1 per thread.
    const int tid = blockIdx.x * TPB + threadIdx.x;
    const int nthreads = gridDim.x * TPB;
    for (int idx = tid; idx < (K * N * K) / 4; idx += nthreads) {
        const int r = idx >> 4;          // row in [0, K*N)
        const int cb = (idx & 15) << 2;  // column base
        const int hot = r >> 8;          // r / N
        f32x4 v;
        v.x = (cb + 0 == hot) ? 1.0f : 0.0f;
        v.y = (cb + 1 == hot) ? 1.0f : 0.0f;
        v.z = (cb + 2 == hot) ? 1.0f : 0.0f;
        v.w = (cb + 3 == hot) ? 1.0f : 0.0f;
        y4[idx] = v;
    }
}

extern "C" void kernel_launch(void* const* d_in, const int* in_sizes, int n_in,
                              void* d_out, int out_size, void* d_ws, size_t ws_size,
                              hipStream_t stream) {
    const float* x = (const float*)d_in[0];
    float* out = (float*)d_out;

    const int B = in_sizes[0] / (K * N);       // 4096
    const int total_chunks = (B * K) / 4;      // 65536 4-segment chunks
    float* pred = out;                         // B*K floats
    float* y = out + (size_t)B * K;            // K*N*K floats

    fused_kernel<<<BLOCKS, TPB, 0, stream>>>(
        reinterpret_cast<const f32x4*>(x), pred,
        reinterpret_cast<f32x4*>(y), total_chunks);
}